// Round 12
// baseline (314.279 us; speedup 1.0000x reference)
//
#include <hip/hip_runtime.h>
#include <hip/hip_bf16.h>
#include <math.h>

typedef unsigned short u16;
typedef unsigned int   u32;
typedef __attribute__((ext_vector_type(8)))  short bf16x8;   // 8 bf16 (4 VGPRs)
typedef __attribute__((ext_vector_type(4)))  float f32x4;
typedef __attribute__((ext_vector_type(16))) float f32x16;

#define B_  2
#define T_  2048
#define C_  2048
#define H_  16
#define HD_ 128
#define M_  4096          // B*T
#define N3C 6144          // 3*C

// ---------- bf16 helpers ----------
__device__ __forceinline__ float bf2f_lo(u32 u) { return __uint_as_float(u << 16); }
__device__ __forceinline__ float bf2f_hi(u32 u) { return __uint_as_float(u & 0xffff0000u); }

__device__ __forceinline__ u16 f2bf(float f) {
    u32 u = __float_as_uint(f);
    return (u16)((u + 0x7fffu + ((u >> 16) & 1u)) >> 16);   // RNE
}
__device__ __forceinline__ u32 pack2(float a, float b) {
    return (u32)f2bf(a) | ((u32)f2bf(b) << 16);
}
__device__ __forceinline__ void store1(float* p, float v) { *p = v; }
__device__ __forceinline__ void store1(__hip_bfloat16* p, float v) { *(u16*)p = f2bf(v); }

// async global->LDS, 16B per lane (wave-uniform LDS base + lane*16)
__device__ __forceinline__ void gload16(const void* g, void* l) {
    __builtin_amdgcn_global_load_lds((__attribute__((address_space(1))) void*)g,
                                     (__attribute__((address_space(3))) void*)l, 16, 0, 0);
}

// hardware sin/cos in revolutions (v_fract range-reduce per ISA doc)
__device__ __forceinline__ void fast_sincos_rev(float rev, float* s, float* c) {
    float fr;
    asm("v_fract_f32 %0, %1" : "=v"(fr) : "v"(rev));
    float sv, cv;
    asm("v_sin_f32 %0, %1" : "=v"(sv) : "v"(fr));
    asm("v_cos_f32 %0, %1" : "=v"(cv) : "v"(fr));
    *s = sv; *c = cv;
}

// ---------- fused fp32 -> bf16 convert of x, Wa, Wp (one launch) ----------
__global__ __launch_bounds__(256) void cvt_all(const float* __restrict__ x,
                                               const float* __restrict__ Wa,
                                               const float* __restrict__ Wp,
                                               u16* __restrict__ xb,
                                               u16* __restrict__ Wab,
                                               u16* __restrict__ Wpb) {
    const int n_x  = M_ * C_ / 8;
    const int n_wa = N3C * C_ / 8;
    const int i = blockIdx.x * 256 + threadIdx.x;
    const float* src; u16* dst; int j;
    if (i < n_x)            { src = x;  dst = xb;  j = i; }
    else if (i < n_x + n_wa){ src = Wa; dst = Wab; j = i - n_x; }
    else                    { src = Wp; dst = Wpb; j = i - n_x - n_wa; }
    const float4 a = ((const float4*)src)[2 * j];
    const float4 b = ((const float4*)src)[2 * j + 1];
    ((uint4*)dst)[j] = make_uint4(pack2(a.x, a.y), pack2(a.z, a.w),
                                  pack2(b.x, b.y), pack2(b.z, b.w));
}

// ---------- 256x256 8-phase-style pipelined GEMM (NT): C[m,n]=sum_k A[m,k]W[n,k] ----------
// 512 thr = 8 waves (2M x 4N), wave tile 128x64; BK=64; double-buffered linear LDS
// (128 KB); 4 phases per K-tile, ONE 16KB stage unit (2 gload_lds) per phase;
// counted vmcnt(4) only at each tile's last phase (never drains in-loop).
// Stage schedule (tile t computed from buf d=t&1):
//   p0: A-h0(t+1)->buf[d^1]   (A of t-1 fully read at its p3, two barriers prior)
//   p1: A-h1(t+1)->buf[d^1]
//   p2: B-h0(t+2)->buf[d]     (B of t fully read at p0, two barriers prior)
//   p3: B-h1(t+2)->buf[d]
// vmcnt(4) at p3 forces A(t+1)+B(t+1) landed (B(t+1) is older), leaves 2 units
// in flight; [vmcnt; s_barrier] gives cross-wave visibility before t+1's reads.
// B-frags are read once per K-tile (p0) and held in registers across phases.
template <typename TO, bool ROPE>
__global__ __launch_bounds__(512, 1) void gemm_8ph(const __hip_bfloat16* __restrict__ A,
                                                   const __hip_bfloat16* __restrict__ W,
                                                   TO* __restrict__ Cout,
                                                   int N, int K, int gx) {
    __shared__ u16 As[2][256 * 64];   // 64 KB
    __shared__ u16 Bs[2][256 * 64];   // 64 KB
    const int nwg = gridDim.x * gridDim.y;
    const int id  = blockIdx.y * gx + blockIdx.x;
    const int swz = (id & 7) * (nwg >> 3) + (id >> 3);
    const int bm  = (swz / gx) * 256;
    const int bn  = (swz % gx) * 256;

    const int tid  = threadIdx.x;
    const int w    = tid >> 6;        // 0..7
    const int lane = tid & 63;
    const int g    = lane >> 4;       // 0..3
    const int c    = lane & 15;       // 0..15
    const int wm   = w >> 2;          // 0..1  (A-rows wm*128..+128)
    const int wn   = w & 3;           // 0..3  (B-cols wn*64..+64)

    const int sr = lane >> 3;         // 0..7  staging row within 8-row strip
    const int sc = (lane & 7) * 8;    // 0..56 staging col

    const __hip_bfloat16* Ag = A + (size_t)bm * K;
    const __hip_bfloat16* Wg = W + (size_t)bn * K;

    // one stage unit = 128 rows x 64 cols bf16 = 16 KB; wave w covers rows
    // [h*128 + w*16, +16) via two 1KB gload_lds (8 rows each)
#define SA_(d_, h_, k0_) do {                                                              \
    gload16(Ag + (size_t)((h_) * 128 + w * 16 + sr) * K + (k0_) + sc,                      \
            &As[d_][((h_) * 128 + w * 16) * 64]);                                          \
    gload16(Ag + (size_t)((h_) * 128 + w * 16 + 8 + sr) * K + (k0_) + sc,                  \
            &As[d_][((h_) * 128 + w * 16 + 8) * 64]);                                      \
} while (0)
#define SB_(d_, h_, k0_) do {                                                              \
    gload16(Wg + (size_t)((h_) * 128 + w * 16 + sr) * K + (k0_) + sc,                      \
            &Bs[d_][((h_) * 128 + w * 16) * 64]);                                          \
    gload16(Wg + (size_t)((h_) * 128 + w * 16 + 8 + sr) * K + (k0_) + sc,                  \
            &Bs[d_][((h_) * 128 + w * 16 + 8) * 64]);                                      \
} while (0)

    f32x4 acc[8][4];
#pragma unroll
    for (int mi = 0; mi < 8; ++mi)
#pragma unroll
        for (int ni = 0; ni < 4; ++ni)
            acc[mi][ni] = (f32x4){0.f, 0.f, 0.f, 0.f};

    const int NT = K / 64;            // 32

    // prologue: B(0), A(0), B(1); allow B(1)'s 4 loads in flight
    SB_(0, 0, 0); SB_(0, 1, 0);
    SA_(0, 0, 0); SA_(0, 1, 0);
    SB_(1, 0, 64); SB_(1, 1, 64);
    asm volatile("s_waitcnt vmcnt(4)" ::: "memory");
    __builtin_amdgcn_sched_barrier(0);
    __builtin_amdgcn_s_barrier();
    __builtin_amdgcn_sched_barrier(0);

    for (int t = 0; t < NT; ++t) {
        const int d = t & 1;
        bf16x8 bfr[4][2];
#pragma unroll
        for (int p = 0; p < 4; ++p) {
            // ---- ds-reads for this phase ----
            if (p == 0) {
#pragma unroll
                for (int ni = 0; ni < 4; ++ni)
#pragma unroll
                    for (int kk = 0; kk < 2; ++kk)
                        bfr[ni][kk] = *(const bf16x8*)
                            &Bs[d][(wn * 64 + ni * 16 + c) * 64 + kk * 32 + g * 8];
            }
            bf16x8 af2[2][2];
#pragma unroll
            for (int ml = 0; ml < 2; ++ml)
#pragma unroll
                for (int kk = 0; kk < 2; ++kk)
                    af2[ml][kk] = *(const bf16x8*)
                        &As[d][(wm * 128 + (2 * p + ml) * 16 + c) * 64 + kk * 32 + g * 8];

            // ---- one stage unit per phase ----
            if (p == 0) { if (t + 1 < NT) SA_(d ^ 1, 0, (t + 1) * 64); }
            if (p == 1) { if (t + 1 < NT) SA_(d ^ 1, 1, (t + 1) * 64); }
            if (p == 2) { if (t + 2 < NT) SB_(d,     0, (t + 2) * 64); }
            if (p == 3) { if (t + 2 < NT) SB_(d,     1, (t + 2) * 64); }

            __builtin_amdgcn_sched_barrier(0);
            __builtin_amdgcn_s_barrier();
            __builtin_amdgcn_sched_barrier(0);

            __builtin_amdgcn_s_setprio(1);
#pragma unroll
            for (int ml = 0; ml < 2; ++ml)
#pragma unroll
                for (int ni = 0; ni < 4; ++ni)
#pragma unroll
                    for (int kk = 0; kk < 2; ++kk)
                        acc[2 * p + ml][ni] = __builtin_amdgcn_mfma_f32_16x16x32_bf16(
                            af2[ml][kk], bfr[ni][kk], acc[2 * p + ml][ni], 0, 0, 0);
            __builtin_amdgcn_s_setprio(0);

            if (p == 3) {
                if (t + 2 < NT) { asm volatile("s_waitcnt vmcnt(4)" ::: "memory"); }
                else            { asm volatile("s_waitcnt vmcnt(0)" ::: "memory"); }
            }
            __builtin_amdgcn_sched_barrier(0);
            __builtin_amdgcn_s_barrier();
            __builtin_amdgcn_sched_barrier(0);
        }
    }
#undef SA_
#undef SB_

    // fused RoPE on q/k thirds (cols < 4096; bn is a multiple of 256)
    if (ROPE && bn < 2 * C_) {
#pragma unroll
        for (int ni = 0; ni < 4; ++ni) {
            const int col = wn * 64 + ni * 16 + c;
            const int ip = (col >> 1) & 63;
            const float tp = exp2f(-(float)ip * 0.20762050593046f - 2.6514961294723187f);
            const float sgn = (c & 1) ? 1.f : -1.f;
#pragma unroll
            for (int mi = 0; mi < 8; ++mi)
#pragma unroll
                for (int i = 0; i < 4; ++i) {
                    const int row = bm + wm * 128 + mi * 16 + 4 * g + i;
                    float s, co;
                    fast_sincos_rev((float)(row & (T_ - 1)) * tp, &s, &co);
                    const float own = acc[mi][ni][i];
                    const float par = __shfl_xor(own, 1);
                    acc[mi][ni][i] = own * co + sgn * par * s;
                }
        }
    }

    // C/D layout: col = lane&15, row = 4*(lane>>4) + i   [verified m89]
#pragma unroll
    for (int mi = 0; mi < 8; ++mi)
#pragma unroll
        for (int ni = 0; ni < 4; ++ni)
#pragma unroll
            for (int i = 0; i < 4; ++i) {
                const int row = bm + wm * 128 + mi * 16 + 4 * g + i;
                const int col = bn + wn * 64 + ni * 16 + c;
                store1(Cout + (size_t)row * N + col, acc[mi][ni][i]);
            }
}

// ---------- 128x128 pipelined bf16 GEMM (round-6 verified) — GEMM2 ----------
template <typename TO>
__global__ __launch_bounds__(256, 3) void gemm_pipe(const __hip_bfloat16* __restrict__ A,
                                                    const __hip_bfloat16* __restrict__ W,
                                                    TO* __restrict__ Cout,
                                                    int N, int K, int gx) {
    __shared__ u16 As[3][128 * 32];
    __shared__ u16 Bs[3][128 * 32];
    const int nwg = gridDim.x * gridDim.y;
    const int id  = blockIdx.y * gx + blockIdx.x;
    const int swz = (id & 7) * (nwg >> 3) + (id >> 3);
    const int bm  = (swz / gx) * 128;
    const int bn  = (swz % gx) * 128;

    const int tid  = threadIdx.x;
    const int w    = tid >> 6;
    const int lane = tid & 63;
    const int g    = lane >> 4;
    const int c    = lane & 15;
    const int wr   = (w >> 1) * 64;
    const int wc   = (w & 1) * 64;

    const int srow = lane >> 2;
    const int scol = (lane & 3) * 8;
    const __hip_bfloat16* ga0 = A + (size_t)(bm + w * 32 + srow) * K + scol;
    const __hip_bfloat16* ga1 = ga0 + (size_t)16 * K;
    const __hip_bfloat16* gb0 = W + (size_t)(bn + w * 32 + srow) * K + scol;
    const __hip_bfloat16* gb1 = gb0 + (size_t)16 * K;

#define STAGE_(bi, kk) do {                                   \
        gload16(ga0 + (kk), &As[bi][w * 1024]);               \
        gload16(ga1 + (kk), &As[bi][w * 1024 + 512]);         \
        gload16(gb0 + (kk), &Bs[bi][w * 1024]);               \
        gload16(gb1 + (kk), &Bs[bi][w * 1024 + 512]);         \
    } while (0)

    f32x4 acc[4][4];
#pragma unroll
    for (int mi = 0; mi < 4; ++mi)
#pragma unroll
        for (int ni = 0; ni < 4; ++ni)
            acc[mi][ni] = (f32x4){0.f, 0.f, 0.f, 0.f};

    const int NT = K / 32;
    STAGE_(0, 0);
    STAGE_(1, 32);

    int cur = 0;
    for (int t = 0; t < NT; ++t) {
        if (t + 1 < NT) { asm volatile("s_waitcnt vmcnt(4)" ::: "memory"); }
        else            { asm volatile("s_waitcnt vmcnt(0)" ::: "memory"); }
        __builtin_amdgcn_sched_barrier(0);
        __builtin_amdgcn_s_barrier();
        __builtin_amdgcn_sched_barrier(0);

        if (t + 2 < NT) {
            const int nb = (cur + 2 >= 3) ? cur - 1 : cur + 2;
            STAGE_(nb, (t + 2) * 32);
        }

        bf16x8 af[4], bfr[4];
#pragma unroll
        for (int mi = 0; mi < 4; ++mi)
            af[mi] = *(const bf16x8*)&As[cur][(wr + mi * 16 + c) * 32 + g * 8];
#pragma unroll
        for (int ni = 0; ni < 4; ++ni)
            bfr[ni] = *(const bf16x8*)&Bs[cur][(wc + ni * 16 + c) * 32 + g * 8];

        __builtin_amdgcn_s_setprio(1);
#pragma unroll
        for (int mi = 0; mi < 4; ++mi)
#pragma unroll
            for (int ni = 0; ni < 4; ++ni)
                acc[mi][ni] = __builtin_amdgcn_mfma_f32_16x16x32_bf16(
                    af[mi], bfr[ni], acc[mi][ni], 0, 0, 0);
        __builtin_amdgcn_s_setprio(0);

        cur = (cur + 1 == 3) ? 0 : cur + 1;
    }
#undef STAGE_

#pragma unroll
    for (int mi = 0; mi < 4; ++mi)
#pragma unroll
        for (int ni = 0; ni < 4; ++ni)
#pragma unroll
            for (int i = 0; i < 4; ++i) {
                const int row = bm + wr + mi * 16 + 4 * g + i;
                const int col = bn + wc + ni * 16 + c;
                store1(Cout + (size_t)row * N + col, acc[mi][ni][i]);
            }
}

// ---------- fallback reg-staged GEMM (fp32 or bf16 sources) ----------
__device__ __forceinline__ void stage_tile(u16* dst, const float* src, int ldk, int tid) {
    const int r0  = tid >> 3;
    const int off = (tid & 7) * 4;
#pragma unroll
    for (int it = 0; it < 4; ++it) {
        const int row = r0 + it * 32;
        const float4 v = *(const float4*)(src + (size_t)row * ldk + off);
        *(uint2*)&dst[row * 40 + off] = make_uint2(pack2(v.x, v.y), pack2(v.z, v.w));
    }
}
__device__ __forceinline__ void stage_tile(u16* dst, const __hip_bfloat16* src, int ldk, int tid) {
    const int r0  = tid >> 2;
    const int off = (tid & 3) * 8;
#pragma unroll
    for (int it = 0; it < 2; ++it) {
        const int row = r0 + it * 64;
        *(uint4*)&dst[row * 40 + off] = *(const uint4*)(src + (size_t)row * ldk + off);
    }
}

template <typename TA, typename TW, typename TO>
__global__ __launch_bounds__(256) void gemm_mfma(const TA* __restrict__ A,
                                                 const TW* __restrict__ W,
                                                 TO* __restrict__ Cout,
                                                 int N, int K, int gx) {
    __shared__ u16 As[128 * 40];
    __shared__ u16 Bs[128 * 40];
    const int nwg = gridDim.x * gridDim.y;
    const int id  = blockIdx.y * gx + blockIdx.x;
    const int swz = (id & 7) * (nwg >> 3) + (id >> 3);
    const int bm  = (swz / gx) * 128;
    const int bn  = (swz % gx) * 128;

    const int tid  = threadIdx.x;
    const int w    = tid >> 6;
    const int lane = tid & 63;
    const int g    = lane >> 4;
    const int c    = lane & 15;
    const int wr   = (w >> 1) * 64;
    const int wc   = (w & 1) * 64;

    f32x4 acc[4][4];
#pragma unroll
    for (int mi = 0; mi < 4; ++mi)
#pragma unroll
        for (int ni = 0; ni < 4; ++ni)
            acc[mi][ni] = (f32x4){0.f, 0.f, 0.f, 0.f};

    const TA* Ab = A + (size_t)bm * K;
    const TW* Wb = W + (size_t)bn * K;

    for (int k0 = 0; k0 < K; k0 += 32) {
        __syncthreads();
        stage_tile(As, Ab + k0, K, tid);
        stage_tile(Bs, Wb + k0, K, tid);
        __syncthreads();

        bf16x8 af[4], bfr[4];
#pragma unroll
        for (int mi = 0; mi < 4; ++mi)
            af[mi] = *(const bf16x8*)&As[(wr + mi * 16 + c) * 40 + g * 8];
#pragma unroll
        for (int ni = 0; ni < 4; ++ni)
            bfr[ni] = *(const bf16x8*)&Bs[(wc + ni * 16 + c) * 40 + g * 8];
#pragma unroll
        for (int mi = 0; mi < 4; ++mi)
#pragma unroll
            for (int ni = 0; ni < 4; ++ni)
                acc[mi][ni] = __builtin_amdgcn_mfma_f32_16x16x32_bf16(
                    af[mi], bfr[ni], acc[mi][ni], 0, 0, 0);
    }

#pragma unroll
    for (int mi = 0; mi < 4; ++mi)
#pragma unroll
        for (int ni = 0; ni < 4; ++ni)
#pragma unroll
            for (int i = 0; i < 4; ++i) {
                const int row = bm + wr + mi * 16 + 4 * g + i;
                const int col = bn + wc + ni * 16 + c;
                store1(Cout + (size_t)row * N + col, acc[mi][ni][i]);
            }
}

// ---------- RoPE in-place on q,k thirds of qkv (bf16) — fallback path only ----------
__global__ __launch_bounds__(256) void rope_kernel(__hip_bfloat16* __restrict__ qkv) {
    const int id  = blockIdx.x * 256 + threadIdx.x;
    const int i   = id & 63;
    const int h   = (id >> 6) & (H_ - 1);
    const int qk  = (id >> 10) & 1;
    const int row = id >> 11;
    const int t   = row & (T_ - 1);
    const size_t base = (size_t)row * N3C + (size_t)qk * C_ + h * HD_ + 2 * i;
    u32* p = (u32*)((u16*)qkv + base);
    const u32 v = *p;
    const float x0 = bf2f_lo(v), x1 = bf2f_hi(v);
    const float l2th = 0.20762050593046f;               // log2(10000)/64
    const float theta = exp2f(-(float)i * l2th);
    const float ang = (float)t * theta;
    float s, cc;
    sincosf(ang, &s, &cc);
    *p = pack2(x0 * cc - x1 * s, x1 * cc + x0 * s);
}

// ---------- MFMA causal flash attention, 32x32 swapped-QK (round-11) ----------
__device__ __forceinline__ int PI_(int s) {
    return (s & 51) | ((s & 4) << 1) | ((s & 8) >> 1);
}

__global__ __launch_bounds__(256, 2) void attn_mfma2(const __hip_bfloat16* __restrict__ qkv,
                                                     __hip_bfloat16* __restrict__ y) {
    __shared__ u16 Ks[2][64 * 136];
    __shared__ u16 Vt[2][128 * 72];
    __shared__ float Red[128];

    const int tid  = threadIdx.x;
    const int w    = tid >> 6;
    const int lane = tid & 63;
    const int c31  = lane & 31;
    const int hi   = lane >> 5;
    const int bid  = blockIdx.x;
    const int bh   = bid & 31;
    const int qb   = (bid < 256) ? 15 - (bid >> 5) : (bid >> 5) - 8;
    const int b    = bh >> 4, h = bh & 15;
    const int q0   = qb * 128;

    const size_t base = (size_t)b * T_ * N3C + (size_t)h * HD_;
    const __hip_bfloat16* Qp = qkv + base;
    const __hip_bfloat16* Kp = qkv + base + C_;
    const __hip_bfloat16* Vp = qkv + base + 2 * C_;

    bf16x8 qf[8];
    {
        const size_t qoff = (size_t)(q0 + w * 32 + c31) * N3C + hi * 8;
#pragma unroll
        for (int kc = 0; kc < 8; ++kc)
            qf[kc] = *(const bf16x8*)(Qp + qoff + kc * 16);
    }

    f32x16 o[4];
#pragma unroll
    for (int db = 0; db < 4; ++db)
#pragma unroll
        for (int r = 0; r < 16; ++r) o[db][r] = 0.f;

    float m_ = -1e30f, l_ = 0.f;
    const int   myq   = q0 + w * 32 + c31;
    const float SCALE = 0.08838834764831845f;   // 1/sqrt(128)

    const int s_   = tid >> 2;
    const int dsub = tid & 3;
    const int vcol = PI_(s_) ^ (dsub << 4);

    uint4 kreg[4], vreg[4];
#pragma unroll
    for (int it = 0; it < 4; ++it) {
        const int col = dsub * 32 + it * 8;
        const size_t goff = (size_t)s_ * N3C + col;
        kreg[it] = *(const uint4*)(Kp + goff);
        vreg[it] = *(const uint4*)(Vp + goff);
    }

    const int nkt = 2 * qb + 2;
    for (int kt = 0; kt < nkt; ++kt) {
        const int pb = kt & 1;
#pragma unroll
        for (int it = 0; it < 4; ++it) {
            const int col = dsub * 32 + it * 8;
            *(uint4*)&Ks[pb][s_ * 136 + col] = kreg[it];
            const u32 vw[4] = {vreg[it].x, vreg[it].y, vreg[it].z, vreg[it].w};
#pragma unroll
            for (int j = 0; j < 8; ++j)
                Vt[pb][(col + j) * 72 + vcol] = (u16)(vw[j >> 1] >> ((j & 1) * 16));
        }
        if (kt + 1 < nkt) {
#pragma unroll
            for (int it = 0; it < 4; ++it) {
                const int col = dsub * 32 + it * 8;
                const size_t goff = (size_t)((kt + 1) * 64 + s_) * N3C + col;
                kreg[it] = *(const uint4*)(Kp + goff);
                vreg[it] = *(const uint4*)(Vp + goff);
            }
        }
        __syncthreads();

        const int k0 = kt * 64;
        f32x16 sA, sB;
#pragma unroll
        for (int r = 0; r < 16; ++r) { sA[r] = 0.f; sB[r] = 0.f; }
        __builtin_amdgcn_s_setprio(1);
#pragma unroll
        for (int kc = 0; kc < 8; ++kc) {
            const bf16x8 ka = *(const bf16x8*)&Ks[pb][c31 * 136 + kc * 16 + hi * 8];
            sA = __builtin_amdgcn_mfma_f32_32x32x16_bf16(ka, qf[kc], sA, 0, 0, 0);
            const bf16x8 kb_ = *(const bf16x8*)&Ks[pb][(32 + c31) * 136 + kc * 16 + hi * 8];
            sB = __builtin_amdgcn_mfma_f32_32x32x16_bf16(kb_, qf[kc], sB, 0, 0, 0);
        }
        __builtin_amdgcn_s_setprio(0);

        float pmax = -1e30f;
#pragma unroll
        for (int r = 0; r < 16; ++r) {
            const int cr = (r & 3) + 8 * (r >> 2) + 4 * hi;
            sA[r] = (k0 + cr      <= myq) ? sA[r] * SCALE : -1e30f;
            sB[r] = (k0 + 32 + cr <= myq) ? sB[r] * SCALE : -1e30f;
            pmax = fmaxf(pmax, fmaxf(sA[r], sB[r]));
        }
        pmax = fmaxf(pmax, __shfl_xor(pmax, 32));

        if (__any(pmax > m_ + 8.f)) {           // T13 defer-max
            const float mn   = fmaxf(m_, pmax);
            const float corr = __expf(m_ - mn);
            Red[w * 32 + c31] = corr;
            float cf[16];
#pragma unroll
            for (int r = 0; r < 16; ++r)
                cf[r] = Red[w * 32 + ((r & 3) + 8 * (r >> 2) + 4 * hi)];
#pragma unroll
            for (int db = 0; db < 4; ++db)
#pragma unroll
                for (int r = 0; r < 16; ++r) o[db][r] *= cf[r];
            l_ *= corr;
            m_ = mn;
        }

        float psum = 0.f;
#pragma unroll
        for (int r = 0; r < 16; ++r) {
            sA[r] = __expf(sA[r] - m_); psum += sA[r];
            sB[r] = __expf(sB[r] - m_); psum += sB[r];
        }
        psum += __shfl_xor(psum, 32);
        l_ += psum;

        __builtin_amdgcn_s_setprio(1);
#pragma unroll
        for (int kb2 = 0; kb2 < 2; ++kb2) {
#pragma unroll
            for (int c2 = 0; c2 < 2; ++c2) {
                union { u32 u[4]; bf16x8 v; } pk;
#pragma unroll
                for (int q2 = 0; q2 < 4; ++q2) {
                    const int r = 8 * c2 + 2 * q2;
                    const float e0 = kb2 ? sB[r]     : sA[r];
                    const float e1 = kb2 ? sB[r + 1] : sA[r + 1];
                    pk.u[q2] = pack2(e0, e1);
                }
#pragma unroll
                for (int db = 0; db < 4; ++db) {
                    const int colb = (kb2 * 32 + c2 * 16 + hi * 8) ^ (db << 4);
                    const bf16x8 vb = *(const bf16x8*)&Vt[pb][(db * 32 + c31) * 72 + colb];
                    o[db] = __builtin_amdgcn_mfma_f32_32x32x16_bf16(pk.v, vb, o[db], 0, 0, 0);
                }
            }
        }
        __builtin_amdgcn_s_setprio(0);
    }

    Red[w * 32 + c31] = l_;
    float lv[16];
#pragma unroll
    for (int r = 0; r < 16; ++r)
        lv[r] = 1.f / Red[w * 32 + ((r & 3) + 8 * (r >> 2) + 4 * hi)];
#pragma unroll
    for (int db = 0; db < 4; ++db)
#pragma unroll
        for (int r = 0; r < 16; ++r) {
            const int q = q0 + w * 32 + (r & 3) + 8 * (r >> 2) + 4 * hi;
            store1(y + (size_t)(b * T_ + q) * C_ + h * HD_ + db * 32 + c31,
                   o[db][r] * lv[r]);
        }
}

// ---------- launch ----------
extern "C" void kernel_launch(void* const* d_in, const int* in_sizes, int n_in,
                              void* d_out, int out_size, void* d_ws, size_t ws_size,
                              hipStream_t stream) {
    const float* x  = (const float*)d_in[0];          // [B,T,C] fp32
    // d_in[1] = causal mask (analytic) -> unused
    const float* Wa = (const float*)d_in[2];          // [3C,C] fp32
    const float* Wp = (const float*)d_in[3];          // [C,C] fp32
    float* out = (float*)d_out;                       // [B,T,C] fp32

    u16* ws = (u16*)d_ws;
    __hip_bfloat16* qkv = (__hip_bfloat16*)ws;                       // [4096,6144] bf16
    __hip_bfloat16* y   = (__hip_bfloat16*)(ws + (size_t)M_ * N3C);  // [4096,2048] bf16

    const size_t NEED = ((size_t)M_ * N3C + (size_t)M_ * C_ +        // qkv + y
                         (size_t)M_ * C_ +                           // xb
                         (size_t)N3C * C_ + (size_t)C_ * C_) * 2;    // Wab + Wpb

    if (ws_size >= NEED) {
        u16* xb  = ws + (size_t)M_ * N3C + (size_t)M_ * C_;
        u16* Wab = xb + (size_t)M_ * C_;
        u16* Wpb = Wab + (size_t)N3C * C_;

        const int n8_total = (M_ * C_ + N3C * C_ + C_ * C_) / 8;     // 3,145,728
        cvt_all<<<n8_total / 256, 256, 0, stream>>>(x, Wa, Wp, xb, Wab, Wpb);

        gemm_8ph<__hip_bfloat16, true>
            <<<dim3(N3C / 256, M_ / 256), 512, 0, stream>>>(
                (const __hip_bfloat16*)xb, (const __hip_bfloat16*)Wab, qkv, N3C, C_, N3C / 256);
        attn_mfma2<<<512, 256, 0, stream>>>(qkv, y);
        gemm_pipe<float>
            <<<dim3(C_ / 128, M_ / 128), 256, 0, stream>>>(
                y, (const __hip_bfloat16*)Wpb, out, C_, C_, C_ / 128);
    } else {
        gemm_mfma<float, float, __hip_bfloat16>
            <<<dim3(N3C / 128, M_ / 128), 256, 0, stream>>>(x, Wa, qkv, N3C, C_, N3C / 128);
        rope_kernel<<<(M_ * C_) / 256, 256, 0, stream>>>(qkv);
        attn_mfma2<<<512, 256, 0, stream>>>(qkv, y);
        gemm_mfma<__hip_bfloat16, float, float>
            <<<dim3(C_ / 128, M_ / 128), 256, 0, stream>>>(y, Wp, out, C_, C_, C_ / 128);
    }
}

// Round 13
// 288.970 us; speedup vs baseline: 1.0876x; 1.0876x over previous
//
#include <hip/hip_runtime.h>
#include <hip/hip_bf16.h>
#include <math.h>

typedef unsigned short u16;
typedef unsigned int   u32;
typedef __attribute__((ext_vector_type(8)))  short bf16x8;   // 8 bf16 (4 VGPRs)
typedef __attribute__((ext_vector_type(4)))  float f32x4;
typedef __attribute__((ext_vector_type(16))) float f32x16;

#define B_  2
#define T_  2048
#define C_  2048
#define H_  16
#define HD_ 128
#define M_  4096          // B*T
#define N3C 6144          // 3*C

// ---------- bf16 helpers ----------
__device__ __forceinline__ float bf2f_lo(u32 u) { return __uint_as_float(u << 16); }
__device__ __forceinline__ float bf2f_hi(u32 u) { return __uint_as_float(u & 0xffff0000u); }

__device__ __forceinline__ u16 f2bf(float f) {
    u32 u = __float_as_uint(f);
    return (u16)((u + 0x7fffu + ((u >> 16) & 1u)) >> 16);   // RNE
}
__device__ __forceinline__ u32 pack2(float a, float b) {
    return (u32)f2bf(a) | ((u32)f2bf(b) << 16);
}
__device__ __forceinline__ void store1(float* p, float v) { *p = v; }
__device__ __forceinline__ void store1(__hip_bfloat16* p, float v) { *(u16*)p = f2bf(v); }

// async global->LDS, 16B per lane (wave-uniform LDS base + lane*16)
__device__ __forceinline__ void gload16(const void* g, void* l) {
    __builtin_amdgcn_global_load_lds((__attribute__((address_space(1))) void*)g,
                                     (__attribute__((address_space(3))) void*)l, 16, 0, 0);
}

// hardware sin/cos in revolutions (v_fract range-reduce per ISA doc)
__device__ __forceinline__ void fast_sincos_rev(float rev, float* s, float* c) {
    float fr;
    asm("v_fract_f32 %0, %1" : "=v"(fr) : "v"(rev));
    float sv, cv;
    asm("v_sin_f32 %0, %1" : "=v"(sv) : "v"(fr));
    asm("v_cos_f32 %0, %1" : "=v"(cv) : "v"(fr));
    *s = sv; *c = cv;
}

// ---------- fused fp32 -> bf16 convert of x, Wa, Wp (one launch) ----------
__global__ __launch_bounds__(256) void cvt_all(const float* __restrict__ x,
                                               const float* __restrict__ Wa,
                                               const float* __restrict__ Wp,
                                               u16* __restrict__ xb,
                                               u16* __restrict__ Wab,
                                               u16* __restrict__ Wpb) {
    const int n_x  = M_ * C_ / 8;
    const int n_wa = N3C * C_ / 8;
    const int i = blockIdx.x * 256 + threadIdx.x;
    const float* src; u16* dst; int j;
    if (i < n_x)            { src = x;  dst = xb;  j = i; }
    else if (i < n_x + n_wa){ src = Wa; dst = Wab; j = i - n_x; }
    else                    { src = Wp; dst = Wpb; j = i - n_x - n_wa; }
    const float4 a = ((const float4*)src)[2 * j];
    const float4 b = ((const float4*)src)[2 * j + 1];
    ((uint4*)dst)[j] = make_uint4(pack2(a.x, a.y), pack2(a.z, a.w),
                                  pack2(b.x, b.y), pack2(b.z, b.w));
}

// ---------- 128x128 pipelined bf16 GEMM (NT): C[m,n] = sum_k A[m,k]*W[n,k] ----------
// BK=32, 4 waves; triple-buffered linear LDS; global_load_lds staging;
// one raw s_barrier per K-step; counted vmcnt(4). (round-6 verified structure)
// ROPE: fused interleaved-pair rotation in the epilogue via v_sin/v_cos (HW trans ops).
template <typename TO, bool ROPE>
__global__ __launch_bounds__(256, 3) void gemm_pipe(const __hip_bfloat16* __restrict__ A,
                                                    const __hip_bfloat16* __restrict__ W,
                                                    TO* __restrict__ Cout,
                                                    int N, int K, int gx) {
    __shared__ u16 As[3][128 * 32];
    __shared__ u16 Bs[3][128 * 32];
    const int nwg = gridDim.x * gridDim.y;
    const int id  = blockIdx.y * gx + blockIdx.x;
    const int swz = (id & 7) * (nwg >> 3) + (id >> 3);
    const int bm  = (swz / gx) * 128;
    const int bn  = (swz % gx) * 128;

    const int tid  = threadIdx.x;
    const int w    = tid >> 6;
    const int lane = tid & 63;
    const int g    = lane >> 4;       // 0..3
    const int c    = lane & 15;       // 0..15
    const int wr   = (w >> 1) * 64;
    const int wc   = (w & 1) * 64;

    const int srow = lane >> 2;
    const int scol = (lane & 3) * 8;
    const __hip_bfloat16* ga0 = A + (size_t)(bm + w * 32 + srow) * K + scol;
    const __hip_bfloat16* ga1 = ga0 + (size_t)16 * K;
    const __hip_bfloat16* gb0 = W + (size_t)(bn + w * 32 + srow) * K + scol;
    const __hip_bfloat16* gb1 = gb0 + (size_t)16 * K;

#define STAGE_(bi, kk) do {                                   \
        gload16(ga0 + (kk), &As[bi][w * 1024]);               \
        gload16(ga1 + (kk), &As[bi][w * 1024 + 512]);         \
        gload16(gb0 + (kk), &Bs[bi][w * 1024]);               \
        gload16(gb1 + (kk), &Bs[bi][w * 1024 + 512]);         \
    } while (0)

    f32x4 acc[4][4];
#pragma unroll
    for (int mi = 0; mi < 4; ++mi)
#pragma unroll
        for (int ni = 0; ni < 4; ++ni)
            acc[mi][ni] = (f32x4){0.f, 0.f, 0.f, 0.f};

    const int NT = K / 32;            // >= 3
    STAGE_(0, 0);
    STAGE_(1, 32);

    int cur = 0;
    for (int t = 0; t < NT; ++t) {
        if (t + 1 < NT) { asm volatile("s_waitcnt vmcnt(4)" ::: "memory"); }
        else            { asm volatile("s_waitcnt vmcnt(0)" ::: "memory"); }
        __builtin_amdgcn_sched_barrier(0);
        __builtin_amdgcn_s_barrier();
        __builtin_amdgcn_sched_barrier(0);

        if (t + 2 < NT) {
            const int nb = (cur + 2 >= 3) ? cur - 1 : cur + 2;
            STAGE_(nb, (t + 2) * 32);
        }

        bf16x8 af[4], bfr[4];
#pragma unroll
        for (int mi = 0; mi < 4; ++mi)
            af[mi] = *(const bf16x8*)&As[cur][(wr + mi * 16 + c) * 32 + g * 8];
#pragma unroll
        for (int ni = 0; ni < 4; ++ni)
            bfr[ni] = *(const bf16x8*)&Bs[cur][(wc + ni * 16 + c) * 32 + g * 8];

        __builtin_amdgcn_s_setprio(1);
#pragma unroll
        for (int mi = 0; mi < 4; ++mi)
#pragma unroll
            for (int ni = 0; ni < 4; ++ni)
                acc[mi][ni] = __builtin_amdgcn_mfma_f32_16x16x32_bf16(
                    af[mi], bfr[ni], acc[mi][ni], 0, 0, 0);
        __builtin_amdgcn_s_setprio(0);

        cur = (cur + 1 == 3) ? 0 : cur + 1;
    }
#undef STAGE_

    // fused RoPE on q/k thirds: pair (d, d^1) lives in lanes (c, c^1).
    // theta/2pi = exp2(-ip*log2(1e4)/64 - log2(2pi)); angle_rev = (row mod T) * that.
    if (ROPE && bn < 2 * C_) {
#pragma unroll
        for (int ni = 0; ni < 4; ++ni) {
            const int ip = ((wc + ni * 16 + c) >> 1) & 63;
            const float tp = exp2f(-(float)ip * 0.20762050593046f - 2.6514961294723187f);
            const float sgn = (c & 1) ? 1.f : -1.f;
#pragma unroll
            for (int mi = 0; mi < 4; ++mi)
#pragma unroll
                for (int i = 0; i < 4; ++i) {
                    const int row = bm + wr + mi * 16 + 4 * g + i;
                    float s, co;
                    fast_sincos_rev((float)(row & (T_ - 1)) * tp, &s, &co);
                    const float own = acc[mi][ni][i];
                    const float par = __shfl_xor(own, 1);
                    acc[mi][ni][i] = own * co + sgn * par * s;
                }
        }
    }

    // C/D layout: col = lane&15, row = 4*(lane>>4) + i   [verified m89]
#pragma unroll
    for (int mi = 0; mi < 4; ++mi)
#pragma unroll
        for (int ni = 0; ni < 4; ++ni)
#pragma unroll
            for (int i = 0; i < 4; ++i) {
                const int row = bm + wr + mi * 16 + 4 * g + i;
                const int col = bn + wc + ni * 16 + c;
                store1(Cout + (size_t)row * N + col, acc[mi][ni][i]);
            }
}

// ---------- fallback reg-staged GEMM (fp32 or bf16 sources) ----------
__device__ __forceinline__ void stage_tile(u16* dst, const float* src, int ldk, int tid) {
    const int r0  = tid >> 3;
    const int off = (tid & 7) * 4;
#pragma unroll
    for (int it = 0; it < 4; ++it) {
        const int row = r0 + it * 32;
        const float4 v = *(const float4*)(src + (size_t)row * ldk + off);
        *(uint2*)&dst[row * 40 + off] = make_uint2(pack2(v.x, v.y), pack2(v.z, v.w));
    }
}
__device__ __forceinline__ void stage_tile(u16* dst, const __hip_bfloat16* src, int ldk, int tid) {
    const int r0  = tid >> 2;
    const int off = (tid & 3) * 8;
#pragma unroll
    for (int it = 0; it < 2; ++it) {
        const int row = r0 + it * 64;
        *(uint4*)&dst[row * 40 + off] = *(const uint4*)(src + (size_t)row * ldk + off);
    }
}

template <typename TA, typename TW, typename TO>
__global__ __launch_bounds__(256) void gemm_mfma(const TA* __restrict__ A,
                                                 const TW* __restrict__ W,
                                                 TO* __restrict__ Cout,
                                                 int N, int K, int gx) {
    __shared__ u16 As[128 * 40];
    __shared__ u16 Bs[128 * 40];
    const int nwg = gridDim.x * gridDim.y;
    const int id  = blockIdx.y * gx + blockIdx.x;
    const int swz = (id & 7) * (nwg >> 3) + (id >> 3);
    const int bm  = (swz / gx) * 128;
    const int bn  = (swz % gx) * 128;

    const int tid  = threadIdx.x;
    const int w    = tid >> 6;
    const int lane = tid & 63;
    const int g    = lane >> 4;
    const int c    = lane & 15;
    const int wr   = (w >> 1) * 64;
    const int wc   = (w & 1) * 64;

    f32x4 acc[4][4];
#pragma unroll
    for (int mi = 0; mi < 4; ++mi)
#pragma unroll
        for (int ni = 0; ni < 4; ++ni)
            acc[mi][ni] = (f32x4){0.f, 0.f, 0.f, 0.f};

    const TA* Ab = A + (size_t)bm * K;
    const TW* Wb = W + (size_t)bn * K;

    for (int k0 = 0; k0 < K; k0 += 32) {
        __syncthreads();
        stage_tile(As, Ab + k0, K, tid);
        stage_tile(Bs, Wb + k0, K, tid);
        __syncthreads();

        bf16x8 af[4], bfr[4];
#pragma unroll
        for (int mi = 0; mi < 4; ++mi)
            af[mi] = *(const bf16x8*)&As[(wr + mi * 16 + c) * 40 + g * 8];
#pragma unroll
        for (int ni = 0; ni < 4; ++ni)
            bfr[ni] = *(const bf16x8*)&Bs[(wc + ni * 16 + c) * 40 + g * 8];
#pragma unroll
        for (int mi = 0; mi < 4; ++mi)
#pragma unroll
            for (int ni = 0; ni < 4; ++ni)
                acc[mi][ni] = __builtin_amdgcn_mfma_f32_16x16x32_bf16(
                    af[mi], bfr[ni], acc[mi][ni], 0, 0, 0);
    }

#pragma unroll
    for (int mi = 0; mi < 4; ++mi)
#pragma unroll
        for (int ni = 0; ni < 4; ++ni)
#pragma unroll
            for (int i = 0; i < 4; ++i) {
                const int row = bm + wr + mi * 16 + 4 * g + i;
                const int col = bn + wc + ni * 16 + c;
                store1(Cout + (size_t)row * N + col, acc[mi][ni][i]);
            }
}

// ---------- RoPE in-place on q,k thirds of qkv (bf16) — fallback path only ----------
__global__ __launch_bounds__(256) void rope_kernel(__hip_bfloat16* __restrict__ qkv) {
    const int id  = blockIdx.x * 256 + threadIdx.x;
    const int i   = id & 63;
    const int h   = (id >> 6) & (H_ - 1);
    const int qk  = (id >> 10) & 1;
    const int row = id >> 11;
    const int t   = row & (T_ - 1);
    const size_t base = (size_t)row * N3C + (size_t)qk * C_ + h * HD_ + 2 * i;
    u32* p = (u32*)((u16*)qkv + base);
    const u32 v = *p;
    const float x0 = bf2f_lo(v), x1 = bf2f_hi(v);
    const float l2th = 0.20762050593046f;               // log2(10000)/64
    const float theta = exp2f(-(float)i * l2th);
    const float ang = (float)t * theta;
    float s, cc;
    sincosf(ang, &s, &cc);
    *p = pack2(x0 * cc - x1 * s, x1 * cc + x0 * s);
}

// ---------- MFMA causal flash attention, 32x32 swapped-QK ----------
// Double-buffered K/V LDS -> ONE barrier per K-tile:
//   [write buf(t&1) from regs; issue loads t+1; barrier; compute buf(t&1)]
__device__ __forceinline__ int PI_(int s) {
    return (s & 51) | ((s & 4) << 1) | ((s & 8) >> 1);
}

__global__ __launch_bounds__(256, 2) void attn_mfma2(const __hip_bfloat16* __restrict__ qkv,
                                                     __hip_bfloat16* __restrict__ y) {
    __shared__ u16 Ks[2][64 * 136];
    __shared__ u16 Vt[2][128 * 72];
    __shared__ float Red[128];

    const int tid  = threadIdx.x;
    const int w    = tid >> 6;
    const int lane = tid & 63;
    const int c31  = lane & 31;
    const int hi   = lane >> 5;
    const int bid  = blockIdx.x;
    const int bh   = bid & 31;
    // complementary-length pairing: bid i and bid 256+i sum to 36 K-tiles on a CU
    const int qb   = (bid < 256) ? 15 - (bid >> 5) : (bid >> 5) - 8;
    const int b    = bh >> 4, h = bh & 15;
    const int q0   = qb * 128;

    const size_t base = (size_t)b * T_ * N3C + (size_t)h * HD_;
    const __hip_bfloat16* Qp = qkv + base;
    const __hip_bfloat16* Kp = qkv + base + C_;
    const __hip_bfloat16* Vp = qkv + base + 2 * C_;

    bf16x8 qf[8];
    {
        const size_t qoff = (size_t)(q0 + w * 32 + c31) * N3C + hi * 8;
#pragma unroll
        for (int kc = 0; kc < 8; ++kc)
            qf[kc] = *(const bf16x8*)(Qp + qoff + kc * 16);
    }

    f32x16 o[4];
#pragma unroll
    for (int db = 0; db < 4; ++db)
#pragma unroll
        for (int r = 0; r < 16; ++r) o[db][r] = 0.f;

    float m_ = -1e30f, l_ = 0.f;
    const int   myq   = q0 + w * 32 + c31;
    const float SCALE = 0.08838834764831845f;   // 1/sqrt(128)

    const int s_   = tid >> 2;        // staged key row 0..63
    const int dsub = tid & 3;         // 32-col segment
    const int vcol = PI_(s_) ^ (dsub << 4);

    // T14 async stage: regs hold tile kt while tile kt+1's loads are in flight
    uint4 kreg[4], vreg[4];
#pragma unroll
    for (int it = 0; it < 4; ++it) {
        const int col = dsub * 32 + it * 8;
        const size_t goff = (size_t)s_ * N3C + col;
        kreg[it] = *(const uint4*)(Kp + goff);
        vreg[it] = *(const uint4*)(Vp + goff);
    }

    const int nkt = 2 * qb + 2;
    for (int kt = 0; kt < nkt; ++kt) {
        const int pb = kt & 1;
        // write staged regs -> LDS buf pb (other waves still compute buf pb^1)
#pragma unroll
        for (int it = 0; it < 4; ++it) {
            const int col = dsub * 32 + it * 8;
            *(uint4*)&Ks[pb][s_ * 136 + col] = kreg[it];
            const u32 vw[4] = {vreg[it].x, vreg[it].y, vreg[it].z, vreg[it].w};
#pragma unroll
            for (int j = 0; j < 8; ++j)
                Vt[pb][(col + j) * 72 + vcol] = (u16)(vw[j >> 1] >> ((j & 1) * 16));
        }
        // issue next tile's loads (in flight across barrier + compute)
        if (kt + 1 < nkt) {
#pragma unroll
            for (int it = 0; it < 4; ++it) {
                const int col = dsub * 32 + it * 8;
                const size_t goff = (size_t)((kt + 1) * 64 + s_) * N3C + col;
                kreg[it] = *(const uint4*)(Kp + goff);
                vreg[it] = *(const uint4*)(Vp + goff);
            }
        }
        __syncthreads();              // buf pb complete; prev readers of pb^1 done next iter

        const int k0 = kt * 64;
        f32x16 sA, sB;
#pragma unroll
        for (int r = 0; r < 16; ++r) { sA[r] = 0.f; sB[r] = 0.f; }
        __builtin_amdgcn_s_setprio(1);
#pragma unroll
        for (int kc = 0; kc < 8; ++kc) {
            const bf16x8 ka = *(const bf16x8*)&Ks[pb][c31 * 136 + kc * 16 + hi * 8];
            sA = __builtin_amdgcn_mfma_f32_32x32x16_bf16(ka, qf[kc], sA, 0, 0, 0);
            const bf16x8 kb_ = *(const bf16x8*)&Ks[pb][(32 + c31) * 136 + kc * 16 + hi * 8];
            sB = __builtin_amdgcn_mfma_f32_32x32x16_bf16(kb_, qf[kc], sB, 0, 0, 0);
        }
        __builtin_amdgcn_s_setprio(0);

        float pmax = -1e30f;
#pragma unroll
        for (int r = 0; r < 16; ++r) {
            const int cr = (r & 3) + 8 * (r >> 2) + 4 * hi;
            sA[r] = (k0 + cr      <= myq) ? sA[r] * SCALE : -1e30f;
            sB[r] = (k0 + 32 + cr <= myq) ? sB[r] * SCALE : -1e30f;
            pmax = fmaxf(pmax, fmaxf(sA[r], sB[r]));
        }
        pmax = fmaxf(pmax, __shfl_xor(pmax, 32));

        if (__any(pmax > m_ + 8.f)) {           // T13 defer-max
            const float mn   = fmaxf(m_, pmax);
            const float corr = __expf(m_ - mn);
            Red[w * 32 + c31] = corr;
            float cf[16];
#pragma unroll
            for (int r = 0; r < 16; ++r)
                cf[r] = Red[w * 32 + ((r & 3) + 8 * (r >> 2) + 4 * hi)];
#pragma unroll
            for (int db = 0; db < 4; ++db)
#pragma unroll
                for (int r = 0; r < 16; ++r) o[db][r] *= cf[r];
            l_ *= corr;
            m_ = mn;
        }

        float psum = 0.f;
#pragma unroll
        for (int r = 0; r < 16; ++r) {
            sA[r] = __expf(sA[r] - m_); psum += sA[r];
            sB[r] = __expf(sB[r] - m_); psum += sB[r];
        }
        psum += __shfl_xor(psum, 32);
        l_ += psum;

        __builtin_amdgcn_s_setprio(1);
#pragma unroll
        for (int kb2 = 0; kb2 < 2; ++kb2) {
#pragma unroll
            for (int c2 = 0; c2 < 2; ++c2) {
                union { u32 u[4]; bf16x8 v; } pk;
#pragma unroll
                for (int q2 = 0; q2 < 4; ++q2) {
                    const int r = 8 * c2 + 2 * q2;
                    const float e0 = kb2 ? sB[r]     : sA[r];
                    const float e1 = kb2 ? sB[r + 1] : sA[r + 1];
                    pk.u[q2] = pack2(e0, e1);
                }
#pragma unroll
                for (int db = 0; db < 4; ++db) {
                    const int colb = (kb2 * 32 + c2 * 16 + hi * 8) ^ (db << 4);
                    const bf16x8 vb = *(const bf16x8*)&Vt[pb][(db * 32 + c31) * 72 + colb];
                    o[db] = __builtin_amdgcn_mfma_f32_32x32x16_bf16(pk.v, vb, o[db], 0, 0, 0);
                }
            }
        }
        __builtin_amdgcn_s_setprio(0);
    }

    Red[w * 32 + c31] = l_;
    float lv[16];
#pragma unroll
    for (int r = 0; r < 16; ++r)
        lv[r] = 1.f / Red[w * 32 + ((r & 3) + 8 * (r >> 2) + 4 * hi)];
#pragma unroll
    for (int db = 0; db < 4; ++db)
#pragma unroll
        for (int r = 0; r < 16; ++r) {
            const int q = q0 + w * 32 + (r & 3) + 8 * (r >> 2) + 4 * hi;
            store1(y + (size_t)(b * T_ + q) * C_ + h * HD_ + db * 32 + c31,
                   o[db][r] * lv[r]);
        }
}

// ---------- launch ----------
extern "C" void kernel_launch(void* const* d_in, const int* in_sizes, int n_in,
                              void* d_out, int out_size, void* d_ws, size_t ws_size,
                              hipStream_t stream) {
    const float* x  = (const float*)d_in[0];          // [B,T,C] fp32
    // d_in[1] = causal mask (analytic) -> unused
    const float* Wa = (const float*)d_in[2];          // [3C,C] fp32
    const float* Wp = (const float*)d_in[3];          // [C,C] fp32
    float* out = (float*)d_out;                       // [B,T,C] fp32

    u16* ws = (u16*)d_ws;
    __hip_bfloat16* qkv = (__hip_bfloat16*)ws;                       // [4096,6144] bf16
    __hip_bfloat16* y   = (__hip_bfloat16*)(ws + (size_t)M_ * N3C);  // [4096,2048] bf16

    const size_t NEED = ((size_t)M_ * N3C + (size_t)M_ * C_ +        // qkv + y
                         (size_t)M_ * C_ +                           // xb
                         (size_t)N3C * C_ + (size_t)C_ * C_) * 2;    // Wab + Wpb

    if (ws_size >= NEED) {
        u16* xb  = ws + (size_t)M_ * N3C + (size_t)M_ * C_;
        u16* Wab = xb + (size_t)M_ * C_;
        u16* Wpb = Wab + (size_t)N3C * C_;

        const int n8_total = (M_ * C_ + N3C * C_ + C_ * C_) / 8;     // 3,145,728
        cvt_all<<<n8_total / 256, 256, 0, stream>>>(x, Wa, Wp, xb, Wab, Wpb);

        gemm_pipe<__hip_bfloat16, true>
            <<<dim3(N3C / 128, M_ / 128), 256, 0, stream>>>(
                (const __hip_bfloat16*)xb, (const __hip_bfloat16*)Wab, qkv, N3C, C_, N3C / 128);
        attn_mfma2<<<512, 256, 0, stream>>>(qkv, y);
        gemm_pipe<float, false>
            <<<dim3(C_ / 128, M_ / 128), 256, 0, stream>>>(
                y, (const __hip_bfloat16*)Wpb, out, C_, C_, C_ / 128);
    } else {
        gemm_mfma<float, float, __hip_bfloat16>
            <<<dim3(N3C / 128, M_ / 128), 256, 0, stream>>>(x, Wa, qkv, N3C, C_, N3C / 128);
        rope_kernel<<<(M_ * C_) / 256, 256, 0, stream>>>(qkv);
        attn_mfma2<<<512, 256, 0, stream>>>(qkv, y);
        gemm_mfma<__hip_bfloat16, float, float>
            <<<dim3(C_ / 128, M_ / 128), 256, 0, stream>>>(y, Wp, out, C_, C_, C_ / 128);
    }
}